// Round 15
// baseline (130.005 us; speedup 1.0000x reference)
//
#include <hip/hip_runtime.h>

// PatchMatch brute-force NN on MI355X.
// s,t (4,16,64,64) fp32; descriptor = 3x3 replicate-padded patch, K=144 (pad 160).
// d2(i,j) = qn_i - 2*cross(i,j) + pn_j; argmin_j (ties -> smallest j).
// Outputs (flat, ALL FLOAT32): nnf (4,2,64,64) then nnd (4,1,64,64).
//
// R15: best-known base (R12 build_desc + R11 mfma: SPLITS 4, 32-j tiles,
// double-buffered async DMA) + de-serialization of the two pipes (measured
// 62us = MFMA 31us + LDS 25us SUMMED, i.e. phase-locked):
//  - COMPUTE register-pipelined: next (js,kc) B-frag pair prefetched into
//    regs before current group's MFMAs -> ds_read/MFMA interleaved per wave.
//  - co-resident block generations process tiles rotated by 16 (anti
//    phase-lock); in-lane argmin update made lexicographic so tile order
//    doesn't affect tie-breaking.

#define N_  4
#define C_  16
#define H_  64
#define W_  64
#define HW_ 4096
#define K_  160              // 144 real + 16 zero-pad; 20 chunks of 8
#define SPLITS_M 4           // j-splits; 1024 j per split, 32 tiles of 32
#define KKSTRIDE 528         // f16 per kk block in LDS: 512 data + 16 pad

#define SPLITS_V 4           // fallback j-splits
#define TILES_PER_SPLIT_V 4

typedef _Float16 f16;
typedef _Float16 f16x8 __attribute__((ext_vector_type(8)));
typedef float    f32x4 __attribute__((ext_vector_type(4)));

__device__ __forceinline__ int iclamp(int v, int lo, int hi) {
    return v < lo ? lo : (v > hi ? hi : v);
}

__device__ __forceinline__ void async_ld16(const void* g, void* l) {
    __builtin_amdgcn_global_load_lds(
        (const __attribute__((address_space(1))) unsigned int*)g,
        (__attribute__((address_space(3))) unsigned int*)l, 16, 0, 0);
}

// ---------------------------------------------------------------------------
// Kernel 1: K-major fp16 hi/lo descriptors + squared norms.
// D[(n*20 + kk)*4096 + pix][8], kk = k/8, k = d*16 + c (d = dy*3+dx).
// One block per image row; wave q handles kk = q*5..q*5+4 for all 64 px ->
// every store is a 1KB coalesced wavefront store. grid (64, N_, 2).
// ---------------------------------------------------------------------------
__global__ __launch_bounds__(256)
void build_desc_norms_kernel(const float* __restrict__ s,
                             const float* __restrict__ t,
                             f16* __restrict__ Qh, f16* __restrict__ Ql,
                             f16* __restrict__ Ph, f16* __restrict__ Pl,
                             float* __restrict__ pn,
                             float* __restrict__ qn) {
    const int y0  = blockIdx.x;                 // image row
    const int n   = blockIdx.y;
    const int src = blockIdx.z;                 // 0: t, 1: s
    const float* img = (src ? s : t) + n * (C_ * HW_);
    f16* Dh = src ? Qh : Ph;
    f16* Dl = src ? Ql : Pl;
    float* nrm = src ? qn : pn;

    __shared__ float imgS[3][C_][W_];           // 12 KB: rows y0-1..y0+1
    __shared__ float nS[4][W_];
    const int tid = threadIdx.x;
    #pragma unroll
    for (int k = 0; k < 12; ++k) {
        const int idx = tid + k * 256;          // 0..3071
        const int x = idx & 63, c = (idx >> 6) & 15, r = idx >> 10;  // r 0..2
        const int gy = iclamp(y0 + r - 1, 0, H_ - 1);
        imgS[r][c][x] = img[c * HW_ + gy * W_ + x];
    }
    __syncthreads();

    const int q = tid >> 6, x = tid & 63;       // wave, lane(=pixel x)
    const int pix = y0 * W_ + x;
    float nacc = 0.f;
    #pragma unroll
    for (int u = 0; u < 5; ++u) {
        const int kk = q * 5 + u;               // 0..19
        f16x8 hv, lv;
        if (kk < 18) {
            const int d  = kk >> 1;             // 0..8
            const int c0 = (kk & 1) * 8;
            const int dy = (d * 11) >> 5;       // d/3 for d in [0,8]
            const int dx = d - dy * 3;
            const int xs = iclamp(x + dx - 1, 0, W_ - 1);
            #pragma unroll
            for (int cc = 0; cc < 8; ++cc) {
                const float v = imgS[dy][c0 + cc][xs];
                const f16 h = (f16)v;
                hv[cc] = h;
                lv[cc] = (f16)(v - (float)h);
                nacc += v * v;
            }
        } else {
            #pragma unroll
            for (int cc = 0; cc < 8; ++cc) { hv[cc] = (f16)0.f; lv[cc] = (f16)0.f; }
        }
        const size_t off = ((size_t)(n * 20 + kk) * HW_ + pix) * 8;
        *(f16x8*)&Dh[off] = hv;                 // 64 lanes x 16B contiguous
        *(f16x8*)&Dl[off] = lv;
    }
    nS[q][x] = nacc;
    __syncthreads();
    if (tid < W_)
        nrm[n * HW_ + pix] = nS[0][tid] + nS[1][tid] + nS[2][tid] + nS[3][tid];
}

// ---------------------------------------------------------------------------
// Kernel 2: MFMA GEMM + fused argmin. 1D grid 512 blocks (split=bid&3 for
// XCD affinity, n=(bid>>2)&3, iblk=bid>>4); block = 4 waves, wave 32 i
// (is=2), block 128 i. j: 32-wide LDS tiles x32/split, double-buffered
// async DMA, register-pipelined COMPUTE. LDS per buffer: [kk 0..19]
// [h rows 0..31 | l rows 0..31][8 f16], KKSTRIDE=528.
// mfma_f32_16x16x32_f16: A/B [idx=lane&15][k=quad*8+e]; C col=lane&15,
// row=quad*4+reg (verified layouts).
// ---------------------------------------------------------------------------
__global__ __launch_bounds__(256)
void mfma_nn_kernel(const f16* __restrict__ Qh, const f16* __restrict__ Ql,
                    const f16* __restrict__ Ph, const f16* __restrict__ Pl,
                    const float* __restrict__ pn_g,
                    unsigned long long* __restrict__ partial) {
    const int bid   = blockIdx.x;
    const int split = bid & 3;          // fixed XCD under round-robin
    const int n     = (bid >> 2) & 3;
    const int iblk  = bid >> 4;         // 0..31
    const int phase = (bid >> 8) & 1;   // co-resident generation
    const int tid  = threadIdx.x;
    const int wave = tid >> 6, lane = tid & 63;
    const int m = lane & 15, quad = lane >> 4;
    const int irow0 = iblk * 128 + wave * 32;

    __shared__ f16 B0[20 * KKSTRIDE];   // 21120 B each
    __shared__ f16 B1[20 * KKSTRIDE];
    __shared__ float pnS[1024];         // this split's pn

    // ---- A fragments, resident (80 regs) ----
    f16x8 Ah[2][5], Al[2][5];
    #pragma unroll
    for (int is = 0; is < 2; ++is)
        #pragma unroll
        for (int kc = 0; kc < 5; ++kc) {
            const size_t off = ((size_t)(n * 20 + kc * 4 + quad) * HW_ +
                                irow0 + is * 16 + m) * 8;
            Ah[is][kc] = *(const f16x8*)(Qh + off);
            Al[is][kc] = *(const f16x8*)(Ql + off);
        }

    const int jsplit0 = split * 1024;
    #pragma unroll
    for (int k = 0; k < 4; ++k)
        pnS[tid + k * 256] = pn_g[n * HW_ + jsplit0 + tid + k * 256];

    float    bd[2][4];
    unsigned bj[2][4];
    #pragma unroll
    for (int is = 0; is < 2; ++is)
        #pragma unroll
        for (int rg = 0; rg < 4; ++rg) { bd[is][rg] = 3.0e38f; bj[is][rg] = ~0u; }

    const int skk  = wave * 5;          // this wave's kk range
    const int srow = lane & 31;
    const f16* sbase = (lane >> 5) ? Pl : Ph;

    // tile order rotated per generation: anti phase-lock on shared CU
    #define TILE(T) (((T) + (phase << 4)) & 31)

    #define STAGE(BUF, T)                                                     \
        {   _Pragma("unroll")                                                 \
            for (int u = 0; u < 5; ++u) {                                     \
                const int kk = skk + u;                                       \
                const f16* g = sbase + ((size_t)(n * 20 + kk) * HW_ +         \
                                        jsplit0 + (T) * 32 + srow) * 8;       \
                async_ld16(g, (void*)&BUF[kk * KKSTRIDE + lane * 8]);         \
            }                                                                 \
        }

    // register-pipelined: prefetch group g+1's B pair before group g's MFMAs
    #define COMPUTE(BUF, T)                                                   \
        {   f32x4 Cf[2][2];                                                   \
            Cf[0][0] = (f32x4){0.f, 0.f, 0.f, 0.f};                           \
            Cf[0][1] = (f32x4){0.f, 0.f, 0.f, 0.f};                           \
            Cf[1][0] = (f32x4){0.f, 0.f, 0.f, 0.f};                           \
            Cf[1][1] = (f32x4){0.f, 0.f, 0.f, 0.f};                           \
            f16x8 cbh, cbl, nbh, nbl;                                         \
            cbh = *(const f16x8*)&BUF[quad * KKSTRIDE + m * 8];               \
            cbl = *(const f16x8*)&BUF[quad * KKSTRIDE + m * 8 + 256];         \
            _Pragma("unroll")                                                 \
            for (int g = 0; g < 10; ++g) {                                    \
                const int js = g / 5, kc = g - js * 5;                        \
                if (g < 9) {                                                  \
                    const int gn = g + 1;                                     \
                    const int jsn = gn / 5, kcn = gn - jsn * 5;               \
                    const int kbn = (kcn * 4 + quad) * KKSTRIDE +             \
                                    (jsn * 16 + m) * 8;                      \
                    nbh = *(const f16x8*)&BUF[kbn];                           \
                    nbl = *(const f16x8*)&BUF[kbn + 256];                     \
                }                                                             \
                _Pragma("unroll")                                             \
                for (int is = 0; is < 2; ++is) {                              \
                    Cf[is][js] = __builtin_amdgcn_mfma_f32_16x16x32_f16(      \
                        Ah[is][kc], cbh, Cf[is][js], 0, 0, 0);                \
                    Cf[is][js] = __builtin_amdgcn_mfma_f32_16x16x32_f16(      \
                        Al[is][kc], cbh, Cf[is][js], 0, 0, 0);                \
                    Cf[is][js] = __builtin_amdgcn_mfma_f32_16x16x32_f16(      \
                        Ah[is][kc], cbl, Cf[is][js], 0, 0, 0);                \
                }                                                             \
                cbh = nbh; cbl = nbl;                                         \
            }                                                                 \
            _Pragma("unroll")                                                 \
            for (int js = 0; js < 2; ++js) {                                  \
                const unsigned jloc = (unsigned)((T) * 32 + js * 16 + m);     \
                const float pnv = pnS[jloc];                                  \
                _Pragma("unroll")                                             \
                for (int is = 0; is < 2; ++is)                                \
                    _Pragma("unroll")                                         \
                    for (int rg = 0; rg < 4; ++rg) {                          \
                        const float d = fmaf(Cf[is][js][rg], -2.f, pnv);      \
                        const bool take = (d < bd[is][rg]) ||                 \
                            (d == bd[is][rg] && jloc < bj[is][rg]);           \
                        bd[is][rg] = take ? d : bd[is][rg];                   \
                        bj[is][rg] = take ? jloc : bj[is][rg];                \
                    }                                                         \
            }                                                                 \
        }

    STAGE(B0, TILE(0))
    asm volatile("s_waitcnt vmcnt(0)" ::: "memory");
    __syncthreads();

    for (int tl = 0; tl < 32; tl += 2) {
        if (tl + 1 < 32) STAGE(B1, TILE(tl + 1))   // DMA overlaps compute
        COMPUTE(B0, TILE(tl))
        asm volatile("s_waitcnt vmcnt(0)" ::: "memory");
        __syncthreads();
        if (tl + 2 < 32) STAGE(B0, TILE(tl + 2))
        COMPUTE(B1, TILE(tl + 1))
        asm volatile("s_waitcnt vmcnt(0)" ::: "memory");
        __syncthreads();
    }
    #undef STAGE
    #undef COMPUTE
    #undef TILE

    // ---- reduce across the 16 m-lanes (same quad = same i rows) ----
    #pragma unroll
    for (int is = 0; is < 2; ++is)
        #pragma unroll
        for (int rg = 0; rg < 4; ++rg) {
            float    d = bd[is][rg];
            unsigned j = (unsigned)jsplit0 + bj[is][rg];
            #pragma unroll
            for (int off = 1; off < 16; off <<= 1) {
                const float    od = __shfl_xor(d, off, 64);
                const unsigned oj = __shfl_xor(j, off, 64);
                const bool take = (od < d) || (od == d && oj < j);
                d = take ? od : d;
                j = take ? oj : j;
            }
            if (m == 0) {
                const int i = irow0 + is * 16 + quad * 4 + rg;
                partial[(size_t)(split * N_ + n) * HW_ + i] =
                    ((unsigned long long)j << 32) |
                    (unsigned long long)__float_as_uint(d);
            }
        }
}

// ---------------------------------------------------------------------------
// Kernel 3: reduce splits, add qn, decode, write outputs (float32)
// ---------------------------------------------------------------------------
__global__ __launch_bounds__(256)
void finalize_mfma_kernel(const unsigned long long* __restrict__ partial,
                          const float* __restrict__ qn_g,
                          float* __restrict__ out) {
    const int id  = blockIdx.x * 256 + threadIdx.x;   // 0..16383
    const int n   = id >> 12;
    const int pix = id & 4095;
    float    bd = 3.0e38f;
    unsigned bj = 0u;
    #pragma unroll
    for (int sp = 0; sp < SPLITS_M; ++sp) {
        const unsigned long long v = partial[(size_t)(sp * N_ + n) * HW_ + pix];
        const float    d = __uint_as_float((unsigned)(v & 0xffffffffull));
        const unsigned j = (unsigned)(v >> 32);
        const bool take = (d < bd) || (d == bd && j < bj);
        bd = take ? d : bd;
        bj = take ? j : bj;
    }
    out[n * 2 * HW_ + pix]            = (float)(bj >> 6);          // idy
    out[n * 2 * HW_ + HW_ + pix]      = (float)(bj & 63);          // idx_x
    out[N_ * 2 * HW_ + n * HW_ + pix] = bd + qn_g[n * HW_ + pix];  // nnd
}

// ===========================================================================
// Fallback path (fp32 vector) + helpers — unchanged
// ===========================================================================
__global__ __launch_bounds__(256)
void prep_norms_kernel(const float* __restrict__ s,
                       const float* __restrict__ t,
                       float* __restrict__ pn,
                       float* __restrict__ qn) {
    const int gid   = blockIdx.x * 256 + threadIdx.x;
    const int which = gid >> 14;
    const int id    = gid & 16383;
    const int n     = id >> 12;
    const int pix   = id & 4095;
    const int y = pix >> 6, x = pix & 63;
    const float* base = (which ? s : t) + n * (C_ * HW_);
    float acc = 0.f;
    for (int c = 0; c < C_; ++c) {
        const float* bc = base + c * HW_;
        #pragma unroll
        for (int dy = 0; dy < 3; ++dy) {
            const float* br = bc + iclamp(y + dy - 1, 0, H_ - 1) * W_;
            #pragma unroll
            for (int dx = 0; dx < 3; ++dx) {
                float v = br[iclamp(x + dx - 1, 0, W_ - 1)];
                acc += v * v;
            }
        }
    }
    (which ? qn : pn)[id] = acc;
}

__global__ __launch_bounds__(256)
void patchmatch_main_kernel(const float* __restrict__ s,
                            const float* __restrict__ t,
                            const float* __restrict__ pn_g,
                            const float* __restrict__ qn_g,
                            unsigned long long* __restrict__ partial) {
    const int yq    = blockIdx.x;
    const int n     = blockIdx.y;
    const int split = blockIdx.z;
    const int tid  = threadIdx.x;
    const int tx   = tid & 15;
    const int ty   = tid >> 4;
    const int i0   = ty * 4;
    const int jrow = tx >> 2;
    const int jx0  = (tx & 3) * 16;

    __shared__ float qS[C_][3][68];
    __shared__ float tS[C_][6][68];
    __shared__ float qnS[W_];

    const float* sb = s + n * (C_ * HW_);
    const float* tb = t + n * (C_ * HW_);

    #pragma unroll
    for (int k = 0; k < 3; ++k) {
        const int id = tid + k * 256;
        const int sg = id & 15;
        const int c  = (id >> 4) & 15;
        const int r  = id >> 8;
        const int gr = iclamp(yq + r - 1, 0, H_ - 1);
        const float4 v = *(const float4*)&sb[c * HW_ + gr * W_ + sg * 4];
        float* dst = &qS[c][r][1 + sg * 4];
        dst[0] = v.x; dst[1] = v.y; dst[2] = v.z; dst[3] = v.w;
    }
    if (tid < 48) {
        const int c  = tid & 15;
        const int r  = tid >> 4;
        const int gr = iclamp(yq + r - 1, 0, H_ - 1);
        qS[c][r][0]  = sb[c * HW_ + gr * W_];
        qS[c][r][65] = sb[c * HW_ + gr * W_ + 63];
    }
    if (tid < W_) qnS[tid] = qn_g[n * HW_ + yq * W_ + tid];

    unsigned long long best[4] = {~0ull, ~0ull, ~0ull, ~0ull};

    for (int ytl = 0; ytl < TILES_PER_SPLIT_V; ++ytl) {
        const int yt = split * TILES_PER_SPLIT_V + ytl;
        __syncthreads();
        #pragma unroll
        for (int k = 0; k < 6; ++k) {
            const int id = tid + k * 256;
            const int sg = id & 15;
            const int c  = (id >> 4) & 15;
            const int r  = id >> 8;
            const int gr = iclamp(4 * yt + r - 1, 0, H_ - 1);
            const float4 v = *(const float4*)&tb[c * HW_ + gr * W_ + sg * 4];
            float* dst = &tS[c][r][1 + sg * 4];
            dst[0] = v.x; dst[1] = v.y; dst[2] = v.z; dst[3] = v.w;
        }
        if (tid < 96) {
            const int c  = tid & 15;
            const int r  = tid >> 4;
            const int gr = iclamp(4 * yt + r - 1, 0, H_ - 1);
            tS[c][r][0]  = tb[c * HW_ + gr * W_];
            tS[c][r][65] = tb[c * HW_ + gr * W_ + 63];
        }
        __syncthreads();

        float acc[4][16];
        #pragma unroll
        for (int a = 0; a < 4; ++a)
            #pragma unroll
            for (int b = 0; b < 16; ++b) acc[a][b] = 0.f;

        for (int c = 0; c < C_; ++c) {
            #pragma unroll
            for (int dy = 0; dy < 3; ++dy) {
                float qv[6], tv[18];
                *(float4*)&qv[0] = *(const float4*)&qS[c][dy][i0];
                *(float2*)&qv[4] = *(const float2*)&qS[c][dy][i0 + 4];
                const float* trow = &tS[c][jrow + dy][jx0];
                *(float4*)&tv[0]  = *(const float4*)&trow[0];
                *(float4*)&tv[4]  = *(const float4*)&trow[4];
                *(float4*)&tv[8]  = *(const float4*)&trow[8];
                *(float4*)&tv[12] = *(const float4*)&trow[12];
                *(float2*)&tv[16] = *(const float2*)&trow[16];
                #pragma unroll
                for (int dx = 0; dx < 3; ++dx)
                    #pragma unroll
                    for (int a = 0; a < 4; ++a)
                        #pragma unroll
                        for (int b = 0; b < 16; ++b)
                            acc[a][b] += qv[a + dx] * tv[b + dx];
            }
        }

        const int jbase = yt * 256 + jrow * W_ + jx0;
        float pnv[16];
        const float* png = &pn_g[n * HW_ + jbase];
        *(float4*)&pnv[0]  = *(const float4*)&png[0];
        *(float4*)&pnv[4]  = *(const float4*)&png[4];
        *(float4*)&pnv[8]  = *(const float4*)&png[8];
        *(float4*)&pnv[12] = *(const float4*)&png[12];
        #pragma unroll
        for (int a = 0; a < 4; ++a) {
            const float qn = qnS[i0 + a];
            #pragma unroll
            for (int b = 0; b < 16; ++b) {
                const float d2 = qn + pnv[b] - 2.f * acc[a][b];
                unsigned long long cand =
                    ((unsigned long long)__float_as_uint(d2) << 32) |
                    (unsigned)(jbase + b);
                best[a] = cand < best[a] ? cand : best[a];
            }
        }
    }

    #pragma unroll
    for (int a = 0; a < 4; ++a) {
        unsigned long long v = best[a];
        #pragma unroll
        for (int mm = 8; mm >= 1; mm >>= 1) {
            unsigned long long o = __shfl_xor(v, mm, 64);
            v = o < v ? o : v;
        }
        best[a] = v;
    }
    if (tx == 0) {
        #pragma unroll
        for (int a = 0; a < 4; ++a)
            partial[((split * N_ + n) * HW_) + yq * W_ + i0 + a] = best[a];
    }
}

__global__ __launch_bounds__(256)
void finalize_kernel(const unsigned long long* __restrict__ partial,
                     float* __restrict__ out) {
    const int id  = blockIdx.x * 256 + threadIdx.x;
    const int n   = id >> 12;
    const int pix = id & 4095;
    unsigned long long best = ~0ull;
    #pragma unroll
    for (int sp = 0; sp < SPLITS_V; ++sp) {
        unsigned long long v = partial[(sp * N_ + n) * HW_ + pix];
        best = v < best ? v : best;
    }
    const unsigned j = (unsigned)(best & 0xffffffffu);
    const float d2 = __uint_as_float((unsigned)(best >> 32));
    out[n * 2 * HW_ + pix]            = (float)(j >> 6);
    out[n * 2 * HW_ + HW_ + pix]      = (float)(j & 63);
    out[N_ * 2 * HW_ + n * HW_ + pix] = d2;
}

__global__ __launch_bounds__(256)
void patchmatch_mono_kernel(const float* __restrict__ s,
                            const float* __restrict__ t,
                            float* __restrict__ out) {
    const int yq  = blockIdx.x;
    const int n   = blockIdx.y;
    const int tid = threadIdx.x;
    const int tx  = tid & 15;
    const int ty  = tid >> 4;
    const int i0  = ty * 4;
    const int jrow = tx >> 3;
    const int jx0  = (tx & 7) * 8;

    __shared__ float qS[C_][3][68];
    __shared__ float tS[C_][4][68];
    __shared__ float pnS[HW_];
    __shared__ float qnS[W_];

    const float* sb = s + n * (C_ * HW_);
    const float* tb = t + n * (C_ * HW_);

    for (int jj = tid; jj < HW_; jj += 256) {
        const int y = jj >> 6, x = jj & 63;
        float acc = 0.f;
        for (int c = 0; c < C_; ++c) {
            const float* tc = tb + c * HW_;
            #pragma unroll
            for (int dy = 0; dy < 3; ++dy) {
                const float* tr = tc + iclamp(y + dy - 1, 0, H_ - 1) * W_;
                #pragma unroll
                for (int dx = 0; dx < 3; ++dx) {
                    float v = tr[iclamp(x + dx - 1, 0, W_ - 1)];
                    acc += v * v;
                }
            }
        }
        pnS[jj] = acc;
    }
    for (int idx = tid; idx < C_ * 3 * 66; idx += 256) {
        const int c   = idx / (3 * 66);
        const int rem = idx - c * (3 * 66);
        const int rr  = rem / 66;
        const int xi  = rem - rr * 66;
        qS[c][rr][xi] = sb[c * HW_ + iclamp(yq + rr - 1, 0, H_ - 1) * W_ +
                           iclamp(xi - 1, 0, W_ - 1)];
    }
    __syncthreads();
    if (tid < W_) {
        float acc = 0.f;
        for (int c = 0; c < C_; ++c)
            #pragma unroll
            for (int dy = 0; dy < 3; ++dy)
                #pragma unroll
                for (int dx = 0; dx < 3; ++dx) {
                    float v = qS[c][dy][tid + dx];
                    acc += v * v;
                }
        qnS[tid] = acc;
    }

    unsigned long long best[4] = {~0ull, ~0ull, ~0ull, ~0ull};
    for (int yt = 0; yt < 32; ++yt) {
        __syncthreads();
        for (int idx = tid; idx < C_ * 4 * 66; idx += 256) {
            const int c   = idx / (4 * 66);
            const int rem = idx - c * (4 * 66);
            const int rr  = rem / 66;
            const int xi  = rem - rr * 66;
            tS[c][rr][xi] = tb[c * HW_ + iclamp(2 * yt + rr - 1, 0, H_ - 1) * W_ +
                               iclamp(xi - 1, 0, W_ - 1)];
        }
        __syncthreads();

        float acc[4][8];
        #pragma unroll
        for (int a = 0; a < 4; ++a)
            #pragma unroll
            for (int b = 0; b < 8; ++b) acc[a][b] = 0.f;

        for (int c = 0; c < C_; ++c) {
            #pragma unroll
            for (int dy = 0; dy < 3; ++dy) {
                float qv[8], tv[12];
                *(float4*)&qv[0] = *(const float4*)&qS[c][dy][i0];
                *(float4*)&qv[4] = *(const float4*)&qS[c][dy][i0 + 4];
                const float* trow = &tS[c][jrow + dy][jx0];
                *(float4*)&tv[0] = *(const float4*)&trow[0];
                *(float4*)&tv[4] = *(const float4*)&trow[4];
                *(float4*)&tv[8] = *(const float4*)&trow[8];
                #pragma unroll
                for (int dx = 0; dx < 3; ++dx)
                    #pragma unroll
                    for (int a = 0; a < 4; ++a)
                        #pragma unroll
                        for (int b = 0; b < 8; ++b)
                            acc[a][b] += qv[a + dx] * tv[b + dx];
            }
        }
        const int rbase = (2 * yt + jrow) * W_ + jx0;
        #pragma unroll
        for (int a = 0; a < 4; ++a) {
            const float qn = qnS[i0 + a];
            #pragma unroll
            for (int b = 0; b < 8; ++b) {
                const int j = rbase + b;
                const float d2 = qn + pnS[j] - 2.f * acc[a][b];
                unsigned long long cand =
                    ((unsigned long long)__float_as_uint(d2) << 32) | (unsigned)j;
                best[a] = cand < best[a] ? cand : best[a];
            }
        }
    }
    #pragma unroll
    for (int a = 0; a < 4; ++a) {
        unsigned long long v = best[a];
        #pragma unroll
        for (int mm = 8; mm >= 1; mm >>= 1) {
            unsigned long long o = __shfl_xor(v, mm, 64);
            v = o < v ? o : v;
        }
        best[a] = v;
    }
    if (tx == 0) {
        #pragma unroll
        for (int a = 0; a < 4; ++a) {
            const int x = i0 + a;
            const unsigned j = (unsigned)(best[a] & 0xffffffffu);
            const float d2 = __uint_as_float((unsigned)(best[a] >> 32));
            const int pix = yq * W_ + x;
            out[n * 2 * HW_ + pix]            = (float)(j >> 6);
            out[n * 2 * HW_ + HW_ + pix]      = (float)(j & 63);
            out[N_ * 2 * HW_ + n * HW_ + pix] = d2;
        }
    }
}

// ===========================================================================
extern "C" void kernel_launch(void* const* d_in, const int* in_sizes, int n_in,
                              void* d_out, int out_size, void* d_ws, size_t ws_size,
                              hipStream_t stream) {
    const float* s = (const float*)d_in[0];
    const float* t = (const float*)d_in[1];
    float* out = (float*)d_out;

    // MFMA ws layout:
    //   pn [4][4096] f32 | qn [4][4096] f32 | partial [4][4][4096] u64 |
    //   Qh | Ql | Ph | Pl   each K-major [4][20][4096][8] f16 (5.24 MB)
    const size_t norm_b  = (size_t)N_ * HW_ * 4;
    const size_t part_b  = (size_t)SPLITS_M * N_ * HW_ * 8;
    const size_t desc_b  = (size_t)N_ * HW_ * K_ * 2;
    const size_t need_m  = 2 * norm_b + part_b + 4 * desc_b;     // ~21.5 MB

    if (ws_size >= need_m) {
        char* w = (char*)d_ws;
        float* pn = (float*)w;                       w += norm_b;
        float* qn = (float*)w;                       w += norm_b;
        unsigned long long* partial = (unsigned long long*)w; w += part_b;
        f16* Qh = (f16*)w;  w += desc_b;
        f16* Ql = (f16*)w;  w += desc_b;
        f16* Ph = (f16*)w;  w += desc_b;
        f16* Pl = (f16*)w;

        build_desc_norms_kernel<<<dim3(64, N_, 2), 256, 0, stream>>>(
            s, t, Qh, Ql, Ph, Pl, pn, qn);
        mfma_nn_kernel<<<512, 256, 0, stream>>>(Qh, Ql, Ph, Pl, pn, partial);
        finalize_mfma_kernel<<<64, 256, 0, stream>>>(partial, qn, out);
        return;
    }

    // Fallback: fp32 vector path
    const size_t need_v = 2 * norm_b + (size_t)SPLITS_V * N_ * HW_ * 8;
    if (ws_size >= need_v) {
        float* pn = (float*)d_ws;
        float* qn = pn + N_ * HW_;
        unsigned long long* partial =
            (unsigned long long*)((char*)d_ws + 2 * norm_b);
        prep_norms_kernel<<<128, 256, 0, stream>>>(s, t, pn, qn);
        dim3 grid(H_, N_, SPLITS_V);
        patchmatch_main_kernel<<<grid, 256, 0, stream>>>(s, t, pn, qn, partial);
        finalize_kernel<<<64, 256, 0, stream>>>(partial, out);
        return;
    }

    dim3 grid(H_, N_);
    patchmatch_mono_kernel<<<grid, 256, 0, stream>>>(s, t, out);
}

// Round 16
// 126.014 us; speedup vs baseline: 1.0317x; 1.0317x over previous
//
#include <hip/hip_runtime.h>
#include <hip/hip_cooperative_groups.h>

namespace cg = cooperative_groups;

// PatchMatch brute-force NN on MI355X.
// s,t (4,16,64,64) fp32; descriptor = 3x3 replicate-padded patch, K=144 (pad 160).
// d2(i,j) = qn_i - 2*cross(i,j) + pn_j; argmin_j (ties -> smallest j).
// Outputs (flat, ALL FLOAT32): nnf (4,2,64,64) then nnd (4,1,64,64).
//
// R16: R11 mfma config is this structure's floor (62us; R12-R15 perturbations
// all worse). Remaining ~59us is build_desc + finalize + ~10us/launch x3.
// => FUSE all three phases into ONE cooperative kernel (grid 512 = 2/CU,
// LDS union 45.7KB) with __threadfence() + grid.sync() between phases
// (documented cross-XCD visibility pattern). Fallback: 3-kernel best-known
// combo (R12 build_desc + R11 mfma) if cooperative launch unavailable.

#define N_  4
#define C_  16
#define H_  64
#define W_  64
#define HW_ 4096
#define K_  160              // 144 real + 16 zero-pad; 20 chunks of 8
#define SPLITS_M 4           // j-splits; 1024 j per split, 32 tiles of 32
#define KKSTRIDE 520         // f16 per kk block in LDS (R11's 62us config)

#define SPLITS_V 4           // fp32 fallback j-splits
#define TILES_PER_SPLIT_V 4

typedef _Float16 f16;
typedef _Float16 f16x8 __attribute__((ext_vector_type(8)));
typedef float    f32x4 __attribute__((ext_vector_type(4)));

__device__ __forceinline__ int iclamp(int v, int lo, int hi) {
    return v < lo ? lo : (v > hi ? hi : v);
}

__device__ __forceinline__ void async_ld16(const void* g, void* l) {
    __builtin_amdgcn_global_load_lds(
        (const __attribute__((address_space(1))) unsigned int*)g,
        (__attribute__((address_space(3))) unsigned int*)l, 16, 0, 0);
}

// ===========================================================================
// Shared phase bodies (used by both the fused kernel and the fallback path)
// ===========================================================================

// Phase 1: K-major fp16 hi/lo descriptors + squared norms for one image row.
// smem must hold >= 3*16*64*4 + 4*64*4 = 13312 B.
__device__ __forceinline__
void desc_phase(char* smem, int y0, int n, int src, int tid,
                const float* __restrict__ s, const float* __restrict__ t,
                f16* __restrict__ Qh, f16* __restrict__ Ql,
                f16* __restrict__ Ph, f16* __restrict__ Pl,
                float* __restrict__ pn, float* __restrict__ qn) {
    float (*imgS)[C_][W_] = (float(*)[C_][W_])smem;          // [3][16][64]
    float (*nS)[W_]       = (float(*)[W_])(smem + 12288);    // [4][64]
    const float* img = (src ? s : t) + n * (C_ * HW_);
    f16* Dh = src ? Qh : Ph;
    f16* Dl = src ? Ql : Pl;
    float* nrm = src ? qn : pn;

    #pragma unroll
    for (int k = 0; k < 12; ++k) {
        const int idx = tid + k * 256;          // 0..3071
        const int x = idx & 63, c = (idx >> 6) & 15, r = idx >> 10;  // r 0..2
        const int gy = iclamp(y0 + r - 1, 0, H_ - 1);
        imgS[r][c][x] = img[c * HW_ + gy * W_ + x];
    }
    __syncthreads();

    const int q = tid >> 6, x = tid & 63;       // wave, lane(=pixel x)
    const int pix = y0 * W_ + x;
    float nacc = 0.f;
    #pragma unroll
    for (int u = 0; u < 5; ++u) {
        const int kk = q * 5 + u;               // 0..19
        f16x8 hv, lv;
        if (kk < 18) {
            const int d  = kk >> 1;             // 0..8
            const int c0 = (kk & 1) * 8;
            const int dy = (d * 11) >> 5;       // d/3 for d in [0,8]
            const int dx = d - dy * 3;
            const int xs = iclamp(x + dx - 1, 0, W_ - 1);
            #pragma unroll
            for (int cc = 0; cc < 8; ++cc) {
                const float v = imgS[dy][c0 + cc][xs];
                const f16 h = (f16)v;
                hv[cc] = h;
                lv[cc] = (f16)(v - (float)h);
                nacc += v * v;
            }
        } else {
            #pragma unroll
            for (int cc = 0; cc < 8; ++cc) { hv[cc] = (f16)0.f; lv[cc] = (f16)0.f; }
        }
        const size_t off = ((size_t)(n * 20 + kk) * HW_ + pix) * 8;
        *(f16x8*)&Dh[off] = hv;                 // 64 lanes x 16B contiguous
        *(f16x8*)&Dl[off] = lv;
    }
    nS[q][x] = nacc;
    __syncthreads();
    if (tid < W_)
        nrm[n * HW_ + pix] = nS[0][tid] + nS[1][tid] + nS[2][tid] + nS[3][tid];
}

// Phase 2: R11 mfma GEMM + fused argmin for one (split, n, iblk).
// smem must hold >= 2*20*KKSTRIDE*2 + 4096 = 45696 B.
__device__ __forceinline__
void mfma_phase(char* smem, int split, int n, int iblk, int tid,
                const f16* __restrict__ Qh, const f16* __restrict__ Ql,
                const f16* __restrict__ Ph, const f16* __restrict__ Pl,
                const float* __restrict__ pn_g,
                unsigned long long* __restrict__ partial) {
    f16*   B0  = (f16*)smem;                         // 20800 B
    f16*   B1  = (f16*)(smem + 20 * KKSTRIDE * 2);   // 20800 B
    float* pnS = (float*)(smem + 40 * KKSTRIDE * 2); //  4096 B

    const int wave = tid >> 6, lane = tid & 63;
    const int m = lane & 15, quad = lane >> 4;
    const int irow0 = iblk * 128 + wave * 32;

    // ---- A fragments, resident (80 regs) ----
    f16x8 Ah[2][5], Al[2][5];
    #pragma unroll
    for (int is = 0; is < 2; ++is)
        #pragma unroll
        for (int kc = 0; kc < 5; ++kc) {
            const size_t off = ((size_t)(n * 20 + kc * 4 + quad) * HW_ +
                                irow0 + is * 16 + m) * 8;
            Ah[is][kc] = *(const f16x8*)(Qh + off);
            Al[is][kc] = *(const f16x8*)(Ql + off);
        }

    const int jsplit0 = split * 1024;
    #pragma unroll
    for (int k = 0; k < 4; ++k)
        pnS[tid + k * 256] = pn_g[n * HW_ + jsplit0 + tid + k * 256];

    float    bd[2][4];
    unsigned bj[2][4];
    #pragma unroll
    for (int is = 0; is < 2; ++is)
        #pragma unroll
        for (int rg = 0; rg < 4; ++rg) { bd[is][rg] = 3.0e38f; bj[is][rg] = 0u; }

    const int skk  = wave * 5;
    const int srow = lane & 31;
    const f16* sbase = (lane >> 5) ? Pl : Ph;

    #define STAGE(BUF, T)                                                     \
        {   _Pragma("unroll")                                                 \
            for (int u = 0; u < 5; ++u) {                                     \
                const int kk = skk + u;                                       \
                const f16* g = sbase + ((size_t)(n * 20 + kk) * HW_ +         \
                                        jsplit0 + (T) * 32 + srow) * 8;       \
                async_ld16(g, (void*)&BUF[kk * KKSTRIDE + lane * 8]);         \
            }                                                                 \
        }

    #define COMPUTE(BUF, T)                                                   \
        {   _Pragma("unroll")                                                 \
            for (int js = 0; js < 2; ++js) {                                  \
                f32x4 Cf[2];                                                  \
                Cf[0] = (f32x4){0.f, 0.f, 0.f, 0.f};                          \
                Cf[1] = (f32x4){0.f, 0.f, 0.f, 0.f};                          \
                _Pragma("unroll")                                             \
                for (int kc = 0; kc < 5; ++kc) {                              \
                    const int kb = (kc * 4 + quad) * KKSTRIDE +               \
                                   (js * 16 + m) * 8;                         \
                    const f16x8 bh = *(const f16x8*)&BUF[kb];                 \
                    const f16x8 bl = *(const f16x8*)&BUF[kb + 256];           \
                    _Pragma("unroll")                                         \
                    for (int is = 0; is < 2; ++is) {                          \
                        Cf[is] = __builtin_amdgcn_mfma_f32_16x16x32_f16(      \
                            Ah[is][kc], bh, Cf[is], 0, 0, 0);                 \
                        Cf[is] = __builtin_amdgcn_mfma_f32_16x16x32_f16(      \
                            Al[is][kc], bh, Cf[is], 0, 0, 0);                 \
                        Cf[is] = __builtin_amdgcn_mfma_f32_16x16x32_f16(      \
                            Ah[is][kc], bl, Cf[is], 0, 0, 0);                 \
                    }                                                         \
                }                                                             \
                const int jloc = (T) * 32 + js * 16 + m;                      \
                const float pnv = pnS[jloc];                                  \
                _Pragma("unroll")                                             \
                for (int is = 0; is < 2; ++is)                                \
                    _Pragma("unroll")                                         \
                    for (int rg = 0; rg < 4; ++rg) {                          \
                        const float d = fmaf(Cf[is][rg], -2.f, pnv);          \
                        if (d < bd[is][rg]) {     /* strict <: earliest j */  \
                            bd[is][rg] = d;                                   \
                            bj[is][rg] = (unsigned)jloc;                      \
                        }                                                     \
                    }                                                         \
            }                                                                 \
        }

    STAGE(B0, 0)
    asm volatile("s_waitcnt vmcnt(0)" ::: "memory");
    __syncthreads();

    for (int jt = 0; jt < 32; jt += 2) {
        if (jt + 1 < 32) STAGE(B1, jt + 1)      // DMA overlaps compute
        COMPUTE(B0, jt)
        asm volatile("s_waitcnt vmcnt(0)" ::: "memory");
        __syncthreads();
        if (jt + 2 < 32) STAGE(B0, jt + 2)
        COMPUTE(B1, jt + 1)
        asm volatile("s_waitcnt vmcnt(0)" ::: "memory");
        __syncthreads();
    }
    #undef STAGE
    #undef COMPUTE

    // ---- reduce across the 16 m-lanes (same quad = same i rows) ----
    #pragma unroll
    for (int is = 0; is < 2; ++is)
        #pragma unroll
        for (int rg = 0; rg < 4; ++rg) {
            float    d = bd[is][rg];
            unsigned j = (unsigned)jsplit0 + bj[is][rg];
            #pragma unroll
            for (int off = 1; off < 16; off <<= 1) {
                const float    od = __shfl_xor(d, off, 64);
                const unsigned oj = __shfl_xor(j, off, 64);
                const bool take = (od < d) || (od == d && oj < j);
                d = take ? od : d;
                j = take ? oj : j;
            }
            if (m == 0) {
                const int i = irow0 + is * 16 + quad * 4 + rg;
                partial[(size_t)(split * N_ + n) * HW_ + i] =
                    ((unsigned long long)j << 32) |
                    (unsigned long long)__float_as_uint(d);
            }
        }
}

// Phase 3: reduce splits, add qn, decode, write outputs (float32).
__device__ __forceinline__
void finalize_phase(int id, const unsigned long long* __restrict__ partial,
                    const float* __restrict__ qn_g, float* __restrict__ out) {
    const int n   = id >> 12;
    const int pix = id & 4095;
    float    bd = 3.0e38f;
    unsigned bj = 0u;
    #pragma unroll
    for (int sp = 0; sp < SPLITS_M; ++sp) {
        const unsigned long long v = partial[(size_t)(sp * N_ + n) * HW_ + pix];
        const float    d = __uint_as_float((unsigned)(v & 0xffffffffull));
        const unsigned j = (unsigned)(v >> 32);
        const bool take = (d < bd) || (d == bd && j < bj);
        bd = take ? d : bd;
        bj = take ? j : bj;
    }
    out[n * 2 * HW_ + pix]            = (float)(bj >> 6);          // idy
    out[n * 2 * HW_ + HW_ + pix]      = (float)(bj & 63);          // idx_x
    out[N_ * 2 * HW_ + n * HW_ + pix] = bd + qn_g[n * HW_ + pix];  // nnd
}

// ===========================================================================
// Fused cooperative kernel: 512 blocks x 256 threads, 3 phases + grid syncs.
// ===========================================================================
__global__ __launch_bounds__(256)
void fused_nn_kernel(const float* __restrict__ s, const float* __restrict__ t,
                     f16* __restrict__ Qh, f16* __restrict__ Ql,
                     f16* __restrict__ Ph, f16* __restrict__ Pl,
                     float* __restrict__ pn, float* __restrict__ qn,
                     unsigned long long* __restrict__ partial,
                     float* __restrict__ out) {
    __shared__ __align__(16) char smem[45696];
    const int bid = blockIdx.x;
    const int tid = threadIdx.x;
    cg::grid_group grid = cg::this_grid();

    // Phase 1: 512 blocks = (y0 0..63) x (n 0..3) x (src 0..1)
    desc_phase(smem, bid & 63, (bid >> 6) & 3, bid >> 8, tid,
               s, t, Qh, Ql, Ph, Pl, pn, qn);
    __threadfence();        // device-scope release (cross-XCD visibility)
    grid.sync();

    // Phase 2: 512 blocks = (split 0..3) x (n 0..3) x (iblk 0..31)
    mfma_phase(smem, bid & 3, (bid >> 2) & 3, bid >> 4, tid,
               Qh, Ql, Ph, Pl, pn, partial);
    __threadfence();
    grid.sync();

    // Phase 3: first 64 blocks decode + write outputs
    if (bid < 64) finalize_phase(bid * 256 + tid, partial, qn, out);
}

// ===========================================================================
// Fallback 3-kernel path (R12 build_desc + R11 mfma + finalize)
// ===========================================================================
__global__ __launch_bounds__(256)
void build_desc_norms_kernel(const float* __restrict__ s,
                             const float* __restrict__ t,
                             f16* __restrict__ Qh, f16* __restrict__ Ql,
                             f16* __restrict__ Ph, f16* __restrict__ Pl,
                             float* __restrict__ pn,
                             float* __restrict__ qn) {
    __shared__ __align__(16) char smem[13312];
    desc_phase(smem, blockIdx.x, blockIdx.y, blockIdx.z, threadIdx.x,
               s, t, Qh, Ql, Ph, Pl, pn, qn);
}

__global__ __launch_bounds__(256)
void mfma_nn_kernel(const f16* __restrict__ Qh, const f16* __restrict__ Ql,
                    const f16* __restrict__ Ph, const f16* __restrict__ Pl,
                    const float* __restrict__ pn_g,
                    unsigned long long* __restrict__ partial) {
    __shared__ __align__(16) char smem[45696];
    const int bid = blockIdx.x;
    mfma_phase(smem, bid & 3, (bid >> 2) & 3, bid >> 4, threadIdx.x,
               Qh, Ql, Ph, Pl, pn_g, partial);
}

__global__ __launch_bounds__(256)
void finalize_mfma_kernel(const unsigned long long* __restrict__ partial,
                          const float* __restrict__ qn_g,
                          float* __restrict__ out) {
    finalize_phase(blockIdx.x * 256 + threadIdx.x, partial, qn_g, out);
}

// ===========================================================================
// Last-resort fp32 fallback (no workspace): monolithic vector kernel
// ===========================================================================
__global__ __launch_bounds__(256)
void patchmatch_mono_kernel(const float* __restrict__ s,
                            const float* __restrict__ t,
                            float* __restrict__ out) {
    const int yq  = blockIdx.x;
    const int n   = blockIdx.y;
    const int tid = threadIdx.x;
    const int tx  = tid & 15;
    const int ty  = tid >> 4;
    const int i0  = ty * 4;
    const int jrow = tx >> 3;
    const int jx0  = (tx & 7) * 8;

    __shared__ float qS[C_][3][68];
    __shared__ float tS[C_][4][68];
    __shared__ float pnS[HW_];
    __shared__ float qnS[W_];

    const float* sb = s + n * (C_ * HW_);
    const float* tb = t + n * (C_ * HW_);

    for (int jj = tid; jj < HW_; jj += 256) {
        const int y = jj >> 6, x = jj & 63;
        float acc = 0.f;
        for (int c = 0; c < C_; ++c) {
            const float* tc = tb + c * HW_;
            #pragma unroll
            for (int dy = 0; dy < 3; ++dy) {
                const float* tr = tc + iclamp(y + dy - 1, 0, H_ - 1) * W_;
                #pragma unroll
                for (int dx = 0; dx < 3; ++dx) {
                    float v = tr[iclamp(x + dx - 1, 0, W_ - 1)];
                    acc += v * v;
                }
            }
        }
        pnS[jj] = acc;
    }
    for (int idx = tid; idx < C_ * 3 * 66; idx += 256) {
        const int c   = idx / (3 * 66);
        const int rem = idx - c * (3 * 66);
        const int rr  = rem / 66;
        const int xi  = rem - rr * 66;
        qS[c][rr][xi] = sb[c * HW_ + iclamp(yq + rr - 1, 0, H_ - 1) * W_ +
                           iclamp(xi - 1, 0, W_ - 1)];
    }
    __syncthreads();
    if (tid < W_) {
        float acc = 0.f;
        for (int c = 0; c < C_; ++c)
            #pragma unroll
            for (int dy = 0; dy < 3; ++dy)
                #pragma unroll
                for (int dx = 0; dx < 3; ++dx) {
                    float v = qS[c][dy][tid + dx];
                    acc += v * v;
                }
        qnS[tid] = acc;
    }

    unsigned long long best[4] = {~0ull, ~0ull, ~0ull, ~0ull};
    for (int yt = 0; yt < 32; ++yt) {
        __syncthreads();
        for (int idx = tid; idx < C_ * 4 * 66; idx += 256) {
            const int c   = idx / (4 * 66);
            const int rem = idx - c * (4 * 66);
            const int rr  = rem / 66;
            const int xi  = rem - rr * 66;
            tS[c][rr][xi] = tb[c * HW_ + iclamp(2 * yt + rr - 1, 0, H_ - 1) * W_ +
                               iclamp(xi - 1, 0, W_ - 1)];
        }
        __syncthreads();

        float acc[4][8];
        #pragma unroll
        for (int a = 0; a < 4; ++a)
            #pragma unroll
            for (int b = 0; b < 8; ++b) acc[a][b] = 0.f;

        for (int c = 0; c < C_; ++c) {
            #pragma unroll
            for (int dy = 0; dy < 3; ++dy) {
                float qv[8], tv[12];
                *(float4*)&qv[0] = *(const float4*)&qS[c][dy][i0];
                *(float4*)&qv[4] = *(const float4*)&qS[c][dy][i0 + 4];
                const float* trow = &tS[c][jrow + dy][jx0];
                *(float4*)&tv[0] = *(const float4*)&trow[0];
                *(float4*)&tv[4] = *(const float4*)&trow[4];
                *(float4*)&tv[8] = *(const float4*)&trow[8];
                #pragma unroll
                for (int dx = 0; dx < 3; ++dx)
                    #pragma unroll
                    for (int a = 0; a < 4; ++a)
                        #pragma unroll
                        for (int b = 0; b < 8; ++b)
                            acc[a][b] += qv[a + dx] * tv[b + dx];
            }
        }
        const int rbase = (2 * yt + jrow) * W_ + jx0;
        #pragma unroll
        for (int a = 0; a < 4; ++a) {
            const float qn = qnS[i0 + a];
            #pragma unroll
            for (int b = 0; b < 8; ++b) {
                const int j = rbase + b;
                const float d2 = qn + pnS[j] - 2.f * acc[a][b];
                unsigned long long cand =
                    ((unsigned long long)__float_as_uint(d2) << 32) | (unsigned)j;
                best[a] = cand < best[a] ? cand : best[a];
            }
        }
    }
    #pragma unroll
    for (int a = 0; a < 4; ++a) {
        unsigned long long v = best[a];
        #pragma unroll
        for (int mm = 8; mm >= 1; mm >>= 1) {
            unsigned long long o = __shfl_xor(v, mm, 64);
            v = o < v ? o : v;
        }
        best[a] = v;
    }
    if (tx == 0) {
        #pragma unroll
        for (int a = 0; a < 4; ++a) {
            const int x = i0 + a;
            const unsigned j = (unsigned)(best[a] & 0xffffffffu);
            const float d2 = __uint_as_float((unsigned)(best[a] >> 32));
            const int pix = yq * W_ + x;
            out[n * 2 * HW_ + pix]            = (float)(j >> 6);
            out[n * 2 * HW_ + HW_ + pix]      = (float)(j & 63);
            out[N_ * 2 * HW_ + n * HW_ + pix] = d2;
        }
    }
}

// ===========================================================================
extern "C" void kernel_launch(void* const* d_in, const int* in_sizes, int n_in,
                              void* d_out, int out_size, void* d_ws, size_t ws_size,
                              hipStream_t stream) {
    const float* s = (const float*)d_in[0];
    const float* t = (const float*)d_in[1];
    float* out = (float*)d_out;

    // ws layout: pn [4][4096] f32 | qn [4][4096] f32 | partial [4][4][4096]
    // u64 | Qh | Ql | Ph | Pl each K-major [4][20][4096][8] f16 (5.24 MB)
    const size_t norm_b  = (size_t)N_ * HW_ * 4;
    const size_t part_b  = (size_t)SPLITS_M * N_ * HW_ * 8;
    const size_t desc_b  = (size_t)N_ * HW_ * K_ * 2;
    const size_t need_m  = 2 * norm_b + part_b + 4 * desc_b;     // ~21.5 MB

    if (ws_size >= need_m) {
        char* w = (char*)d_ws;
        float* pn = (float*)w;                       w += norm_b;
        float* qn = (float*)w;                       w += norm_b;
        unsigned long long* partial = (unsigned long long*)w; w += part_b;
        f16* Qh = (f16*)w;  w += desc_b;
        f16* Ql = (f16*)w;  w += desc_b;
        f16* Ph = (f16*)w;  w += desc_b;
        f16* Pl = (f16*)w;

        // Prefer single fused cooperative launch (kills 2 launch gaps).
        int dev = 0;
        (void)hipGetDevice(&dev);
        int coop = 0;
        (void)hipDeviceGetAttribute(&coop, hipDeviceAttributeCooperativeLaunch,
                                    dev);
        int nCU = 0;
        (void)hipDeviceGetAttribute(&nCU, hipDeviceAttributeMultiprocessorCount,
                                    dev);
        int maxBlk = 0;
        (void)hipOccupancyMaxActiveBlocksPerMultiprocessor(
            &maxBlk, (const void*)fused_nn_kernel, 256, 0);

        if (coop && (long long)maxBlk * nCU >= 512) {
            void* args[] = { (void*)&s, (void*)&t, (void*)&Qh, (void*)&Ql,
                             (void*)&Ph, (void*)&Pl, (void*)&pn, (void*)&qn,
                             (void*)&partial, (void*)&out };
            hipError_t err = hipLaunchCooperativeKernel(
                (const void*)fused_nn_kernel, dim3(512), dim3(256), args, 0,
                stream);
            if (err == hipSuccess) return;
            // fall through to 3-kernel path on failure
        }

        build_desc_norms_kernel<<<dim3(64, N_, 2), 256, 0, stream>>>(
            s, t, Qh, Ql, Ph, Pl, pn, qn);
        mfma_nn_kernel<<<512, 256, 0, stream>>>(Qh, Ql, Ph, Pl, pn, partial);
        finalize_mfma_kernel<<<64, 256, 0, stream>>>(partial, qn, out);
        return;
    }

    dim3 grid(H_, N_);
    patchmatch_mono_kernel<<<grid, 256, 0, stream>>>(s, t, out);
}